// Round 11
// baseline (64.151 us; speedup 1.0000x reference)
//
#include <hip/hip_runtime.h>

#define BB 8192
#define TT 50
#define II 50
#define HH 10
#define CC 5

__device__ __forceinline__ float fast_tanh(float x) {
    float e = __expf(2.0f * x);
    return 1.0f - 2.0f * __builtin_amdgcn_rcpf(e + 1.0f);
}

// Broadcast lane ((lane&0x10)|K) within each 32-lane half -> all lanes of the
// 16-lane group see h[K] of their own group. BitMode: offset=(xor<<10)|(or<<5)|and.
#define SWZ(x, K) __uint_as_float((unsigned)__builtin_amdgcn_ds_swizzle( \
    (int)__float_as_uint(x), (((K) << 5) | 0x10)))
#define BC10(H, src)                                                     \
    H[0] = SWZ(src, 0); H[1] = SWZ(src, 1); H[2] = SWZ(src, 2);          \
    H[3] = SWZ(src, 3); H[4] = SWZ(src, 4); H[5] = SWZ(src, 5);          \
    H[6] = SWZ(src, 6); H[7] = SWZ(src, 7); H[8] = SWZ(src, 8);          \
    H[9] = SWZ(src, 9);

// K1: P[t][j][b] = sum_i x[b][t][i] * Wih0[j][i] + (bih0[j]+bhh0[j])
__global__ __launch_bounds__(256) void k_proj0(
    const float* __restrict__ x, const float* __restrict__ Wih0,
    const float* __restrict__ bih0, const float* __restrict__ bhh0,
    float* __restrict__ P) {
    int gid = blockIdx.x * 256 + threadIdx.x;
    int b = gid & (BB - 1);
    int t = gid >> 13;
    const float2* xr = (const float2*)(x + ((size_t)b * TT + t) * II);
    float2 xv[II / 2];
#pragma unroll
    for (int i = 0; i < II / 2; i++) xv[i] = xr[i];
#pragma unroll
    for (int j = 0; j < HH; j++) {
        float a = bih0[j] + bhh0[j];
        const float2* w = (const float2*)(Wih0 + j * II);
#pragma unroll
        for (int i = 0; i < II / 2; i++) {
            float2 wv = w[i];
            a = fmaf(wv.x, xv[i].x, a);
            a = fmaf(wv.y, xv[i].y, a);
        }
        P[((size_t)t * HH + j) * BB + b] = a;
    }
}

// K2: fused 3-layer recurrence + FC, pure f32, register-resident h.
// 16 lanes/batch (lane j<10 owns row j of all weight matrices), 4 batches/wave.
// Cross-lane h broadcast via ds_swizzle (no LDS round-trip on the chain).
// Layers staggered ILP3: iter i runs L0@t=i, L1@t=i-1, L2@t=i-2; all broadcasts
// read the previous iteration's output registers. P prefetch 4-deep.
__global__ __launch_bounds__(256, 2) void k_fused(
    const float* __restrict__ h0all,
    const float* __restrict__ Whh0,
    const float* __restrict__ Wih1, const float* __restrict__ Whh1,
    const float* __restrict__ bih1, const float* __restrict__ bhh1,
    const float* __restrict__ Wih2, const float* __restrict__ Whh2,
    const float* __restrict__ bih2, const float* __restrict__ bhh2,
    const float* __restrict__ fcw, const float* __restrict__ fcb,
    const float* __restrict__ P, float* __restrict__ out) {
    __shared__ __align__(16) float sfc8[TT * HH * 8];   // [t][j][c(pad 8)], 16 KB

    const int tid = threadIdx.x;
    const int j = tid & 15;
    const int g16 = tid >> 4;
    const int b = blockIdx.x * 16 + g16;
    const bool jv = (j < HH);

    // stage padded transposed FC weights: sfc8[(t*HH+j)*8 + c] = fcw[c][t*HH+j]
    for (int idx = tid; idx < TT * HH * 8; idx += 256) {
        int r = idx >> 3, c = idx & 7;
        sfc8[idx] = (c < CC) ? fcw[(size_t)c * (TT * HH) + r] : 0.0f;
    }

    // per-lane weight rows (row j of each matrix); zeros for j >= 10
    float w0[HH], wi1[HH], wh1[HH], wi2[HH], wh2[HH];
    float bs1 = 0.0f, bs2 = 0.0f, h1i = 0.0f, h2i = 0.0f, h0i = 0.0f;
    if (jv) {
#pragma unroll
        for (int k = 0; k < HH; k++) {
            w0[k]  = Whh0[j * HH + k];
            wi1[k] = Wih1[j * HH + k];
            wh1[k] = Whh1[j * HH + k];
            wi2[k] = Wih2[j * HH + k];
            wh2[k] = Whh2[j * HH + k];
        }
        bs1 = bih1[j] + bhh1[j];
        bs2 = bih2[j] + bhh2[j];
        h0i = h0all[(size_t)b * HH + j];
        h1i = h0all[(size_t)BB * HH + (size_t)b * HH + j];
        h2i = h0all[(size_t)2 * BB * HH + (size_t)b * HH + j];
    } else {
#pragma unroll
        for (int k = 0; k < HH; k++) {
            w0[k] = wi1[k] = wh1[k] = wi2[k] = wh2[k] = 0.0f;
        }
    }

    __syncthreads();   // sfc8 ready; waves fully independent afterwards

    // recurrence output registers (read by next iteration's broadcasts)
    float h0o = h0i, h1o = h1i, h2o = h2i;

    float acc[CC] = {0.0f, 0.0f, 0.0f, 0.0f, 0.0f};

    // 4-deep P rotation: p0 = P[t=i], ..., p3 = P[t=i+3]
    float p0 = jv ? P[(size_t)(0 * HH + j) * BB + b] : 0.0f;
    float p1 = jv ? P[(size_t)(1 * HH + j) * BB + b] : 0.0f;
    float p2 = jv ? P[(size_t)(2 * HH + j) * BB + b] : 0.0f;
    float p3 = jv ? P[(size_t)(3 * HH + j) * BB + b] : 0.0f;

#pragma unroll 1
    for (int i = 0; i < TT + 2; i++) {
        // ---- broadcasts of previous-iteration h (30 independent swizzles) ----
        float H0[HH], H1[HH], H2[HH];
        BC10(H0, h0o)
        BC10(H1, h1o)
        BC10(H2, h2o)

        // ---- prefetch P for t = i+4 (clamped; dead beyond t=49) ----
        int tp = (i + 4 < TT) ? (i + 4) : (TT - 1);
        float pnew = jv ? P[(size_t)(tp * HH + j) * BB + b] : 0.0f;

        // ---- FC weights for t = i-2 (clamped; gated below) ----
        int tauc = (i >= 2) ? (i - 2) : 0;
        const float* fb = &sfc8[(tauc * HH + j) * 8];
        float4 f4 = *(const float4*)fb;
        float  f1 = fb[4];

        // ---- three staggered layer rows ----
        float a0 = p0, a1 = bs1, a2 = bs2;
#pragma unroll
        for (int k = 0; k < HH; k++) {
            a0 = fmaf(w0[k],  H0[k], a0);
            a1 = fmaf(wi1[k], H0[k], a1);
            a1 = fmaf(wh1[k], H1[k], a1);
            a2 = fmaf(wi2[k], H1[k], a2);
            a2 = fmaf(wh2[k], H2[k], a2);
        }
        float t0 = fast_tanh(a0);
        float t1 = fast_tanh(a1);
        float t2 = fast_tanh(a2);

        // ---- FC accumulate for t = i-2 (live when i>=2; j>=10 lanes add 0) ----
        if (i >= 2 && jv) {
            float rl = fmaxf(t2, 0.0f);
            acc[0] = fmaf(f4.x, rl, acc[0]);
            acc[1] = fmaf(f4.y, rl, acc[1]);
            acc[2] = fmaf(f4.z, rl, acc[2]);
            acc[3] = fmaf(f4.w, rl, acc[3]);
            acc[4] = fmaf(f1,  rl, acc[4]);
        }

        // ---- commit outputs (init overrides during pipeline fill) ----
        h0o = t0;
        h1o = (i == 0) ? h1i : t1;   // h1(-1) init seen by iter 1
        h2o = (i <= 1) ? h2i : t2;   // h2(-1) init seen by iter 2
        p0 = p1; p1 = p2; p2 = p3; p3 = pnew;
    }

    // reduce acc across the 16-lane group (lanes j>=10 hold zeros)
#pragma unroll
    for (int c = 0; c < CC; c++) {
        float a = acc[c];
        a += __shfl_xor(a, 1);
        a += __shfl_xor(a, 2);
        a += __shfl_xor(a, 4);
        a += __shfl_xor(a, 8);
        acc[c] = a + fcb[c];
    }
    if (j == 0) {
#pragma unroll
        for (int c = 0; c < CC; c++) out[(size_t)b * CC + c] = acc[c];
    }
}

extern "C" void kernel_launch(void* const* d_in, const int* in_sizes, int n_in,
                              void* d_out, int out_size, void* d_ws, size_t ws_size,
                              hipStream_t stream) {
    const float* x    = (const float*)d_in[0];
    const float* h0   = (const float*)d_in[1];
    const float* Wih0 = (const float*)d_in[2];
    const float* Whh0 = (const float*)d_in[3];
    const float* bih0 = (const float*)d_in[4];
    const float* bhh0 = (const float*)d_in[5];
    const float* Wih1 = (const float*)d_in[6];
    const float* Whh1 = (const float*)d_in[7];
    const float* bih1 = (const float*)d_in[8];
    const float* bhh1 = (const float*)d_in[9];
    const float* Wih2 = (const float*)d_in[10];
    const float* Whh2 = (const float*)d_in[11];
    const float* bih2 = (const float*)d_in[12];
    const float* bhh2 = (const float*)d_in[13];
    const float* fcw  = (const float*)d_in[14];
    const float* fcb  = (const float*)d_in[15];
    float* out = (float*)d_out;
    float* P   = (float*)d_ws;   // [T][H][B] = 16.38 MB

    k_proj0<<<(BB * TT) / 256, 256, 0, stream>>>(x, Wih0, bih0, bhh0, P);
    k_fused<<<BB / 16, 256, 0, stream>>>(h0, Whh0, Wih1, Whh1, bih1, bhh1,
                                         Wih2, Whh2, bih2, bhh2, fcw, fcb, P, out);
}